// Round 13
// baseline (831.656 us; speedup 1.0000x reference)
//
#include <hip/hip_runtime.h>
#include <hip/hip_cooperative_groups.h>

namespace cg = cooperative_groups;

// ---------------------------------------------------------------------------
// GCN 2-layer forward. 4 launches:
//   k_csr (cooperative, 2048 blocks = 8/CU co-resident):
//     P0: cnt=0; WT = bf16(W1^T); WT2 = bf16(W2^T) pad [48][128]
//     P1: hist cnt[dst]++ (grid-stride, 524k threads)
//     P2: block-local exscan + dinv   (blocks 0..nb)
//     P3: globalize offsets + cursor  (blocks 0..nb)
//     P4: scatter CSR (src,norm) int2 pairs grouped by dst (grid-stride)
//   k_gemm1:  H1b = bf16(x@W1)   MFMA 16x16x32, LDS-free
//   k_agg1g2: per 64-row block: AGG_lds = bf16(relu(b1 + H1b*dinv^2 +
//             gather(H1b))) -> LDS tile -> MFMA @ WT2 -> H3b
//   k_agg2:   OUT = b2 + H3b*dinv^2 + gather(H3b)
// ---------------------------------------------------------------------------

typedef __attribute__((ext_vector_type(8))) short bf16x8;
typedef __attribute__((ext_vector_type(4))) float f32x4;

__device__ inline unsigned short f2bf(float x) {
    unsigned u = __float_as_uint(x);
    unsigned r = (u + 0x7FFFu + ((u >> 16) & 1u)) >> 16;   // round-nearest-even
    return (unsigned short)r;
}
__device__ inline float bflo(unsigned u) { return __uint_as_float(u << 16); }
__device__ inline float bfhi(unsigned u) { return __uint_as_float(u & 0xFFFF0000u); }

__device__ inline void fma8(float* acc, uint4 uv, float wt) {
    acc[0] = fmaf(bflo(uv.x), wt, acc[0]);
    acc[1] = fmaf(bfhi(uv.x), wt, acc[1]);
    acc[2] = fmaf(bflo(uv.y), wt, acc[2]);
    acc[3] = fmaf(bfhi(uv.y), wt, acc[3]);
    acc[4] = fmaf(bflo(uv.z), wt, acc[4]);
    acc[5] = fmaf(bfhi(uv.z), wt, acc[5]);
    acc[6] = fmaf(bflo(uv.w), wt, acc[6]);
    acc[7] = fmaf(bfhi(uv.w), wt, acc[7]);
}

// single cooperative kernel: entire CSR build. 2048 blocks x 256 threads.
__global__ __launch_bounds__(256) void k_csr(
    const int* __restrict__ src, const int* __restrict__ dst,
    const float* __restrict__ W1, const float* __restrict__ W2,
    int* __restrict__ cnt, int* __restrict__ rowstart,
    int* __restrict__ cursor, int* __restrict__ bsum,
    float* __restrict__ dinv, int2* __restrict__ epair,
    unsigned short* __restrict__ WT, unsigned short* __restrict__ WT2,
    int n, int m, int nb)
{
    cg::grid_group grid = cg::this_grid();
    __shared__ int s[256];
    const int t   = threadIdx.x;
    const int b   = blockIdx.x;
    const int gid = b * 256 + t;
    const int gsz = gridDim.x * 256;

    // P0: zero counts + weight transposes (all independent)
    for (int i = gid; i < n; i += gsz) cnt[i] = 0;
    for (int i = gid; i < 128 * 128; i += gsz) {
        int k = i >> 7, c = i & 127;
        WT[c * 128 + k] = f2bf(W1[i]);
    }
    for (int i = gid; i < 48 * 128; i += gsz) {
        int c = i >> 7, k = i & 127;
        WT2[i] = (c < 40) ? f2bf(W2[k * 40 + c]) : (unsigned short)0;
    }
    grid.sync();

    // P1: degree histogram (latency-bound; full 524k-thread parallelism)
    for (int e = gid; e < m; e += gsz) atomicAdd(&cnt[dst[e]], 1);
    grid.sync();

    // P2: block-local scan + dinv (blocks 0..nb-1; condition block-uniform)
    if (b < nb) {
        int i = b * 256 + t;
        int v = (i < n) ? cnt[i] : 0;
        if (i < n) dinv[i] = rsqrtf((float)v + 1.0f);
        s[t] = v;
        __syncthreads();
#pragma unroll
        for (int off = 1; off < 256; off <<= 1) {
            int x = s[t];
            if (t >= off) x += s[t - off];
            __syncthreads();
            s[t] = x;
            __syncthreads();
        }
        if (i < n) rowstart[i] = s[t] - v;        // block-local exclusive
        if (t == 255) bsum[b] = s[255];
    }
    grid.sync();

    // P3: every scan-block redundantly scans bsum in LDS, globalizes + cursor
    if (b < nb) {
        s[t] = (t < nb) ? bsum[t] : 0;
        __syncthreads();
#pragma unroll
        for (int off = 1; off < 256; off <<= 1) {
            int x = s[t];
            if (t >= off) x += s[t - off];
            __syncthreads();
            s[t] = x;
            __syncthreads();
        }
        int excl = (b > 0) ? s[b - 1] : 0;
        int i = b * 256 + t;
        if (i < n) {
            int v = rowstart[i] + excl;
            rowstart[i] = v;
            cursor[i]   = v;
        }
        if (gid == 0) rowstart[n] = m;
    }
    grid.sync();

    // P4: scatter (src, norm) pairs into CSR order
    for (int e = gid; e < m; e += gsz) {
        int sr = src[e], d = dst[e];
        int pos = atomicAdd(&cursor[d], 1);
        epair[pos] = make_int2(sr, __float_as_int(dinv[sr] * dinv[d]));
    }
}

// GEMM1 via MFMA bf16: 64 rows/block, 4 waves, each wave 16 rows x 128 cols.
__global__ __launch_bounds__(256) void k_gemm1(
    const float* __restrict__ X, const unsigned short* __restrict__ WT,
    unsigned short* __restrict__ Hb, int n)
{
    const int l  = threadIdx.x & 63;
    const int w  = threadIdx.x >> 6;
    const int rw = blockIdx.x * 64 + w * 16;
    const int lr = l & 15;
    const int kq = l >> 4;

    int arow = rw + lr;
    if (arow > n - 1) arow = n - 1;              // clamp: garbage rows never written
    const float* xp = X + (size_t)arow * 128 + kq * 8;

    f32x4 acc[8];
#pragma unroll
    for (int j = 0; j < 8; ++j) acc[j] = (f32x4){0.f, 0.f, 0.f, 0.f};

#pragma unroll
    for (int kk = 0; kk < 4; ++kk) {
        float4 v0 = *(const float4*)(xp + kk * 32);
        float4 v1 = *(const float4*)(xp + kk * 32 + 4);
        bf16x8 a;
        a[0] = (short)f2bf(v0.x); a[1] = (short)f2bf(v0.y);
        a[2] = (short)f2bf(v0.z); a[3] = (short)f2bf(v0.w);
        a[4] = (short)f2bf(v1.x); a[5] = (short)f2bf(v1.y);
        a[6] = (short)f2bf(v1.z); a[7] = (short)f2bf(v1.w);
#pragma unroll
        for (int j = 0; j < 8; ++j) {
            const bf16x8 b = *(const bf16x8*)(WT + (size_t)(j * 16 + lr) * 128 + kk * 32 + kq * 8);
            acc[j] = __builtin_amdgcn_mfma_f32_16x16x32_bf16(a, b, acc[j], 0, 0, 0);
        }
    }

#pragma unroll
    for (int j = 0; j < 8; ++j) {
        int col = j * 16 + lr;
#pragma unroll
        for (int r4 = 0; r4 < 4; ++r4) {
            int rr = rw + kq * 4 + r4;
            if (rr < n) Hb[(size_t)rr * 128 + col] = f2bf(acc[j][r4]);
        }
    }
}

// Fused layer-1 aggregation + GEMM2. 64 rows per 256-thread block.
__global__ __launch_bounds__(256) void k_agg1g2(
    const int* __restrict__ rowstart, const int2* __restrict__ epair,
    const unsigned short* __restrict__ Hb, const float* __restrict__ B1,
    const unsigned short* __restrict__ WT2, const float* __restrict__ dinv,
    unsigned short* __restrict__ H3b, int n)
{
    __shared__ unsigned short tile[64][132];    // bf16, +4 pad
    const int t  = threadIdx.x;
    const int r0 = blockIdx.x * 64;
    const int lane = t & 15;
    const int slot = t >> 4;

    for (int rr = slot; rr < 64; rr += 16) {
        int r = r0 + rr;
        if (r < n) {
            float di = dinv[r], d2 = di * di;
            uint4 hu = *(const uint4*)&Hb[(size_t)r * 128 + lane * 8];
            float a0[8], a1[8] = {}, a2[8] = {}, a3[8] = {};
            {
                const float* bp = &B1[lane * 8];
                float h[8] = {bflo(hu.x), bfhi(hu.x), bflo(hu.y), bfhi(hu.y),
                              bflo(hu.z), bfhi(hu.z), bflo(hu.w), bfhi(hu.w)};
#pragma unroll
                for (int c = 0; c < 8; ++c) a0[c] = fmaf(h[c], d2, bp[c]);
            }
            int j  = rowstart[r];
            int j1 = rowstart[r + 1];
            for (; j + 4 <= j1; j += 4) {
                int2 p0 = epair[j], p1 = epair[j + 1], p2 = epair[j + 2], p3 = epair[j + 3];
                uint4 u0 = *(const uint4*)&Hb[(size_t)p0.x * 128 + lane * 8];
                uint4 u1 = *(const uint4*)&Hb[(size_t)p1.x * 128 + lane * 8];
                uint4 u2 = *(const uint4*)&Hb[(size_t)p2.x * 128 + lane * 8];
                uint4 u3 = *(const uint4*)&Hb[(size_t)p3.x * 128 + lane * 8];
                fma8(a0, u0, __int_as_float(p0.y));
                fma8(a1, u1, __int_as_float(p1.y));
                fma8(a2, u2, __int_as_float(p2.y));
                fma8(a3, u3, __int_as_float(p3.y));
            }
            for (; j < j1; ++j) {
                int2 pe = epair[j];
                uint4 u = *(const uint4*)&Hb[(size_t)pe.x * 128 + lane * 8];
                fma8(a0, u, __int_as_float(pe.y));
            }
            unsigned o[4];
#pragma unroll
            for (int c = 0; c < 4; ++c) {
                float lo = fmaxf(a0[2*c]   + a1[2*c]   + a2[2*c]   + a3[2*c],   0.f);
                float hi = fmaxf(a0[2*c+1] + a1[2*c+1] + a2[2*c+1] + a3[2*c+1], 0.f);
                o[c] = (unsigned)f2bf(lo) | ((unsigned)f2bf(hi) << 16);
            }
            *(uint4*)&tile[rr][lane * 8] = make_uint4(o[0], o[1], o[2], o[3]);
        }
        // rows >= n: tile left uninitialized; MFMA output rows >= n never stored
    }
    __syncthreads();

    // MFMA phase: wave w handles rows rw..rw+15
    const int l  = t & 63;
    const int w  = t >> 6;
    const int rw = r0 + w * 16;
    const int lr = l & 15;
    const int kq = l >> 4;

    f32x4 acc[3];
#pragma unroll
    for (int j = 0; j < 3; ++j) acc[j] = (f32x4){0.f, 0.f, 0.f, 0.f};

#pragma unroll
    for (int kk = 0; kk < 4; ++kk) {
        const bf16x8 a = *(const bf16x8*)&tile[w * 16 + lr][kk * 32 + kq * 8];
#pragma unroll
        for (int j = 0; j < 3; ++j) {
            const bf16x8 b = *(const bf16x8*)(WT2 + (size_t)(j * 16 + lr) * 128 + kk * 32 + kq * 8);
            acc[j] = __builtin_amdgcn_mfma_f32_16x16x32_bf16(a, b, acc[j], 0, 0, 0);
        }
    }

#pragma unroll
    for (int j = 0; j < 3; ++j) {
        int col = j * 16 + lr;
        if (col < 40) {
#pragma unroll
            for (int r4 = 0; r4 < 4; ++r4) {
                int rr = rw + kq * 4 + r4;
                if (rr < n) H3b[(size_t)rr * 40 + col] = f2bf(acc[j][r4]);
            }
        }
    }
}

// layer-2 aggregation: 5 lanes/row, 8 ch each (uint4 = 16B), 320-thread blocks
__global__ __launch_bounds__(320) void k_agg2(
    const int* __restrict__ rowstart, const int2* __restrict__ epair,
    const unsigned short* __restrict__ H3b, const float* __restrict__ B,
    const float* __restrict__ dinv, float* __restrict__ OUT, int n)
{
    int t = threadIdx.x;
    int r = blockIdx.x * 64 + t / 5;
    int q = t % 5;
    if (r >= n) return;
    float di = dinv[r], d2 = di * di;
    uint4 hu = *(const uint4*)&H3b[(size_t)r * 40 + q * 8];
    float a0[8], a1[8] = {}, a2[8] = {}, a3[8] = {};
    {
        const float* bp = &B[q * 8];
        float h[8] = {bflo(hu.x), bfhi(hu.x), bflo(hu.y), bfhi(hu.y),
                      bflo(hu.z), bfhi(hu.z), bflo(hu.w), bfhi(hu.w)};
#pragma unroll
        for (int c = 0; c < 8; ++c) a0[c] = fmaf(h[c], d2, bp[c]);
    }
    int j  = rowstart[r];
    int j1 = rowstart[r + 1];
    for (; j + 4 <= j1; j += 4) {
        int2 p0 = epair[j], p1 = epair[j + 1], p2 = epair[j + 2], p3 = epair[j + 3];
        uint4 u0 = *(const uint4*)&H3b[(size_t)p0.x * 40 + q * 8];
        uint4 u1 = *(const uint4*)&H3b[(size_t)p1.x * 40 + q * 8];
        uint4 u2 = *(const uint4*)&H3b[(size_t)p2.x * 40 + q * 8];
        uint4 u3 = *(const uint4*)&H3b[(size_t)p3.x * 40 + q * 8];
        fma8(a0, u0, __int_as_float(p0.y));
        fma8(a1, u1, __int_as_float(p1.y));
        fma8(a2, u2, __int_as_float(p2.y));
        fma8(a3, u3, __int_as_float(p3.y));
    }
    for (; j < j1; ++j) {
        int2 pe = epair[j];
        uint4 u = *(const uint4*)&H3b[(size_t)pe.x * 40 + q * 8];
        fma8(a0, u, __int_as_float(pe.y));
    }
    float o[8];
#pragma unroll
    for (int c = 0; c < 8; ++c) o[c] = a0[c] + a1[c] + a2[c] + a3[c];
    float* p = &OUT[(size_t)r * 40 + q * 8];
    *(float4*)(p)     = make_float4(o[0], o[1], o[2], o[3]);
    *(float4*)(p + 4) = make_float4(o[4], o[5], o[6], o[7]);
}

extern "C" void kernel_launch(void* const* d_in, const int* in_sizes, int n_in,
                              void* d_out, int out_size, void* d_ws, size_t ws_size,
                              hipStream_t stream) {
    const float* x  = (const float*)d_in[0];
    const int*   ei = (const int*)d_in[1];
    const float* W1 = (const float*)d_in[2];
    const float* b1 = (const float*)d_in[3];
    const float* W2 = (const float*)d_in[4];
    const float* b2 = (const float*)d_in[5];
    float* out = (float*)d_out;

    const int n = in_sizes[0] / 128;     // 50000
    const int m = in_sizes[1] / 2;       // 600000
    const int* src = ei;
    const int* dst = ei + m;
    const int nb = (n + 255) / 256;      // 196

    char* p = (char*)d_ws;
    auto take = [&](size_t bytes) { char* q = p; p += (bytes + 255) & ~(size_t)255; return q; };
    int*   cnt      = (int*)take(sizeof(int) * n);
    int*   rowstart = (int*)take(sizeof(int) * (n + 1));
    int*   cursor   = (int*)take(sizeof(int) * n);
    int*   bsum     = (int*)take(sizeof(int) * 256);
    int2*  epair    = (int2*)take(sizeof(int2) * m);
    float* dinv     = (float*)take(sizeof(float) * n);
    unsigned short* WT  = (unsigned short*)take(sizeof(short) * 128 * 128);
    unsigned short* WT2 = (unsigned short*)take(sizeof(short) * 48 * 128);
    unsigned short* H1b = (unsigned short*)take(sizeof(short) * (size_t)n * 128);
    unsigned short* H3b = (unsigned short*)take(sizeof(short) * (size_t)n * 40);

    {
        // cooperative CSR build: 2048 blocks = 8/CU (1 KB LDS, low VGPR)
        int nn = n, mm = m, nbb = nb;
        void* args[] = {(void*)&src, (void*)&dst, (void*)&W1, (void*)&W2,
                        (void*)&cnt, (void*)&rowstart, (void*)&cursor, (void*)&bsum,
                        (void*)&dinv, (void*)&epair, (void*)&WT, (void*)&WT2,
                        (void*)&nn, (void*)&mm, (void*)&nbb};
        hipLaunchCooperativeKernel((void*)k_csr, dim3(2048), dim3(256), args, 0, stream);
    }

    k_gemm1 <<<(n + 63) / 64, 256, 0, stream>>>(x, WT, H1b, n);
    k_agg1g2<<<(n + 63) / 64, 256, 0, stream>>>(rowstart, epair, H1b, b1, WT2, dinv, H3b, n);
    k_agg2  <<<(n + 63) / 64, 320, 0, stream>>>(rowstart, epair, H3b, b2, dinv, out, n);
}

// Round 14
// 117.017 us; speedup vs baseline: 7.1072x; 7.1072x over previous
//
#include <hip/hip_runtime.h>

// ---------------------------------------------------------------------------
// GCN 2-layer forward. 5 launches, bucket-CSR (no scan, no grid.sync):
//   k_zero:    cnt=0, ovcnt=0; WT = bf16(W1^T); WT2 = bf16(W2^T) pad [48][128]
//   k_scatter: pos = atomicAdd(cnt[dst]); pos<48 ? esrcb[dst*48+pos]=src
//              : overflow list  (hist+scatter in one; no scan needed)
//   k_gemm1:   H1b = bf16(x@W1) MFMA 16x16x32 LDS-free; +196 tail blocks
//              compute dinv = rsqrt(cnt+1)
//   k_agg1g2:  per 64-row block: AGG_lds = bf16(relu(b1 + H1b*dinv^2 +
//              sum_bucket H1b[s]*dinv[s]*dinv[r])) -> LDS -> MFMA @ WT2 -> H3b
//   k_agg2:    OUT = b2 + H3b*dinv^2 + bucket-gather(H3b)
// Norms computed in the aggregators (same fp32 product as before).
// ---------------------------------------------------------------------------

#define CAPC 48

typedef __attribute__((ext_vector_type(8))) short bf16x8;
typedef __attribute__((ext_vector_type(4))) float f32x4;

__device__ inline unsigned short f2bf(float x) {
    unsigned u = __float_as_uint(x);
    unsigned r = (u + 0x7FFFu + ((u >> 16) & 1u)) >> 16;   // round-nearest-even
    return (unsigned short)r;
}
__device__ inline float bflo(unsigned u) { return __uint_as_float(u << 16); }
__device__ inline float bfhi(unsigned u) { return __uint_as_float(u & 0xFFFF0000u); }

__device__ inline void fma8(float* acc, uint4 uv, float wt) {
    acc[0] = fmaf(bflo(uv.x), wt, acc[0]);
    acc[1] = fmaf(bfhi(uv.x), wt, acc[1]);
    acc[2] = fmaf(bflo(uv.y), wt, acc[2]);
    acc[3] = fmaf(bfhi(uv.y), wt, acc[3]);
    acc[4] = fmaf(bflo(uv.z), wt, acc[4]);
    acc[5] = fmaf(bfhi(uv.z), wt, acc[5]);
    acc[6] = fmaf(bflo(uv.w), wt, acc[6]);
    acc[7] = fmaf(bfhi(uv.w), wt, acc[7]);
}

// blocks [0,nb): zero cnt (+ovcnt). [nb,nb+16): WT = W1^T. [nb+16,nb+24): WT2.
__global__ __launch_bounds__(256) void k_zero(int* __restrict__ cnt,
                                              int* __restrict__ ovcnt,
                                              const float* __restrict__ W1,
                                              const float* __restrict__ W2,
                                              unsigned short* __restrict__ WT,
                                              unsigned short* __restrict__ WT2,
                                              int n, int nb) {
    int b = blockIdx.x;
    if (b < nb) {
        int i = b * 256 + threadIdx.x;
        if (i < n) cnt[i] = 0;
        if (b == 0 && threadIdx.x == 0) *ovcnt = 0;
    } else if (b < nb + 16) {
        int idx = (b - nb) * 256 + threadIdx.x;        // 0..4095
        for (int i = idx; i < 128 * 128; i += 4096) {
            int k = i >> 7, c = i & 127;
            WT[c * 128 + k] = f2bf(W1[i]);
        }
    } else {
        int idx = (b - nb - 16) * 256 + threadIdx.x;   // 0..2047
        for (int i = idx; i < 48 * 128; i += 2048) {
            int c = i >> 7, k = i & 127;
            WT2[i] = (c < 40) ? f2bf(W2[k * 40 + c]) : (unsigned short)0;
        }
    }
}

// counting scatter into fixed-capacity buckets; overflow -> (d,s) list
__global__ __launch_bounds__(256) void k_scatter(const int* __restrict__ src,
                                                 const int* __restrict__ dst,
                                                 int* __restrict__ cnt,
                                                 int* __restrict__ esrcb,
                                                 int2* __restrict__ ovbuf,
                                                 int* __restrict__ ovcnt, int m) {
    int e = blockIdx.x * 256 + threadIdx.x;
    if (e >= m) return;
    int s = src[e], d = dst[e];
    int pos = atomicAdd(&cnt[d], 1);
    if (pos < CAPC) {
        esrcb[(size_t)d * CAPC + pos] = s;
    } else {
        int o = atomicAdd(ovcnt, 1);
        ovbuf[o] = make_int2(d, s);
    }
}

// GEMM1 via MFMA bf16 (blocks [0,ngb)); tail blocks compute dinv from cnt.
__global__ __launch_bounds__(256) void k_gemm1(
    const float* __restrict__ X, const unsigned short* __restrict__ WT,
    unsigned short* __restrict__ Hb, const int* __restrict__ cnt,
    float* __restrict__ dinv, int n, int ngb)
{
    if (blockIdx.x >= ngb) {
        int i = (blockIdx.x - ngb) * 256 + threadIdx.x;
        if (i < n) dinv[i] = rsqrtf((float)cnt[i] + 1.0f);
        return;
    }

    const int l  = threadIdx.x & 63;
    const int w  = threadIdx.x >> 6;
    const int rw = blockIdx.x * 64 + w * 16;
    const int lr = l & 15;
    const int kq = l >> 4;

    int arow = rw + lr;
    if (arow > n - 1) arow = n - 1;              // clamp: garbage rows never written
    const float* xp = X + (size_t)arow * 128 + kq * 8;

    f32x4 acc[8];
#pragma unroll
    for (int j = 0; j < 8; ++j) acc[j] = (f32x4){0.f, 0.f, 0.f, 0.f};

#pragma unroll
    for (int kk = 0; kk < 4; ++kk) {
        float4 v0 = *(const float4*)(xp + kk * 32);
        float4 v1 = *(const float4*)(xp + kk * 32 + 4);
        bf16x8 a;
        a[0] = (short)f2bf(v0.x); a[1] = (short)f2bf(v0.y);
        a[2] = (short)f2bf(v0.z); a[3] = (short)f2bf(v0.w);
        a[4] = (short)f2bf(v1.x); a[5] = (short)f2bf(v1.y);
        a[6] = (short)f2bf(v1.z); a[7] = (short)f2bf(v1.w);
#pragma unroll
        for (int j = 0; j < 8; ++j) {
            const bf16x8 b = *(const bf16x8*)(WT + (size_t)(j * 16 + lr) * 128 + kk * 32 + kq * 8);
            acc[j] = __builtin_amdgcn_mfma_f32_16x16x32_bf16(a, b, acc[j], 0, 0, 0);
        }
    }

#pragma unroll
    for (int j = 0; j < 8; ++j) {
        int col = j * 16 + lr;
#pragma unroll
        for (int r4 = 0; r4 < 4; ++r4) {
            int rr = rw + kq * 4 + r4;
            if (rr < n) Hb[(size_t)rr * 128 + col] = f2bf(acc[j][r4]);
        }
    }
}

// Fused layer-1 aggregation + GEMM2, bucket gather. 64 rows / 256-thread block.
__global__ __launch_bounds__(256) void k_agg1g2(
    const int* __restrict__ cnt, const int* __restrict__ esrcb,
    const int2* __restrict__ ovbuf, const int* __restrict__ ovcnt,
    const unsigned short* __restrict__ Hb, const float* __restrict__ B1,
    const unsigned short* __restrict__ WT2, const float* __restrict__ dinv,
    unsigned short* __restrict__ H3b, int n)
{
    __shared__ unsigned short tile[64][132];    // bf16, +4 pad
    const int t  = threadIdx.x;
    const int r0 = blockIdx.x * 64;
    const int lane = t & 15;
    const int slot = t >> 4;
    const int ovn  = *ovcnt;

    for (int rr = slot; rr < 64; rr += 16) {
        int r = r0 + rr;
        if (r < n) {
            float dd = dinv[r], d2 = dd * dd;
            uint4 hu = *(const uint4*)&Hb[(size_t)r * 128 + lane * 8];
            float a0[8], a1[8] = {}, a2[8] = {}, a3[8] = {};
            {
                const float* bp = &B1[lane * 8];
                float h[8] = {bflo(hu.x), bfhi(hu.x), bflo(hu.y), bfhi(hu.y),
                              bflo(hu.z), bfhi(hu.z), bflo(hu.w), bfhi(hu.w)};
#pragma unroll
                for (int c = 0; c < 8; ++c) a0[c] = fmaf(h[c], d2, bp[c]);
            }
            int deg = cnt[r];
            int cap = deg < CAPC ? deg : CAPC;
            const int* ep = esrcb + (size_t)r * CAPC;
            int j = 0;
            for (; j + 4 <= cap; j += 4) {
                int s0 = ep[j], s1 = ep[j + 1], s2 = ep[j + 2], s3 = ep[j + 3];
                uint4 u0 = *(const uint4*)&Hb[(size_t)s0 * 128 + lane * 8];
                uint4 u1 = *(const uint4*)&Hb[(size_t)s1 * 128 + lane * 8];
                uint4 u2 = *(const uint4*)&Hb[(size_t)s2 * 128 + lane * 8];
                uint4 u3 = *(const uint4*)&Hb[(size_t)s3 * 128 + lane * 8];
                fma8(a0, u0, dinv[s0] * dd);
                fma8(a1, u1, dinv[s1] * dd);
                fma8(a2, u2, dinv[s2] * dd);
                fma8(a3, u3, dinv[s3] * dd);
            }
            for (; j < cap; ++j) {
                int s0 = ep[j];
                uint4 u = *(const uint4*)&Hb[(size_t)s0 * 128 + lane * 8];
                fma8(a0, u, dinv[s0] * dd);
            }
            if (ovn > 0) {                      // essentially never taken
                for (int k = 0; k < ovn; ++k) {
                    int2 e = ovbuf[k];
                    if (e.x == r) {
                        uint4 u = *(const uint4*)&Hb[(size_t)e.y * 128 + lane * 8];
                        fma8(a0, u, dinv[e.y] * dd);
                    }
                }
            }
            unsigned o[4];
#pragma unroll
            for (int c = 0; c < 4; ++c) {
                float lo = fmaxf(a0[2*c]   + a1[2*c]   + a2[2*c]   + a3[2*c],   0.f);
                float hi = fmaxf(a0[2*c+1] + a1[2*c+1] + a2[2*c+1] + a3[2*c+1], 0.f);
                o[c] = (unsigned)f2bf(lo) | ((unsigned)f2bf(hi) << 16);
            }
            *(uint4*)&tile[rr][lane * 8] = make_uint4(o[0], o[1], o[2], o[3]);
        }
    }
    __syncthreads();

    // MFMA phase: wave w handles rows rw..rw+15
    const int l  = t & 63;
    const int w  = t >> 6;
    const int rw = r0 + w * 16;
    const int lr = l & 15;
    const int kq = l >> 4;

    f32x4 acc[3];
#pragma unroll
    for (int j = 0; j < 3; ++j) acc[j] = (f32x4){0.f, 0.f, 0.f, 0.f};

#pragma unroll
    for (int kk = 0; kk < 4; ++kk) {
        const bf16x8 a = *(const bf16x8*)&tile[w * 16 + lr][kk * 32 + kq * 8];
#pragma unroll
        for (int j = 0; j < 3; ++j) {
            const bf16x8 b = *(const bf16x8*)(WT2 + (size_t)(j * 16 + lr) * 128 + kk * 32 + kq * 8);
            acc[j] = __builtin_amdgcn_mfma_f32_16x16x32_bf16(a, b, acc[j], 0, 0, 0);
        }
    }

#pragma unroll
    for (int j = 0; j < 3; ++j) {
        int col = j * 16 + lr;
        if (col < 40) {
#pragma unroll
            for (int r4 = 0; r4 < 4; ++r4) {
                int rr = rw + kq * 4 + r4;
                if (rr < n) H3b[(size_t)rr * 40 + col] = f2bf(acc[j][r4]);
            }
        }
    }
}

// layer-2 aggregation: bucket gather, 5 lanes/row, 320-thread blocks
__global__ __launch_bounds__(320) void k_agg2(
    const int* __restrict__ cnt, const int* __restrict__ esrcb,
    const int2* __restrict__ ovbuf, const int* __restrict__ ovcnt,
    const unsigned short* __restrict__ H3b, const float* __restrict__ B,
    const float* __restrict__ dinv, float* __restrict__ OUT, int n)
{
    int t = threadIdx.x;
    int r = blockIdx.x * 64 + t / 5;
    int q = t % 5;
    if (r >= n) return;
    float dd = dinv[r], d2 = dd * dd;
    uint4 hu = *(const uint4*)&H3b[(size_t)r * 40 + q * 8];
    float a0[8], a1[8] = {}, a2[8] = {}, a3[8] = {};
    {
        const float* bp = &B[q * 8];
        float h[8] = {bflo(hu.x), bfhi(hu.x), bflo(hu.y), bfhi(hu.y),
                      bflo(hu.z), bfhi(hu.z), bflo(hu.w), bfhi(hu.w)};
#pragma unroll
        for (int c = 0; c < 8; ++c) a0[c] = fmaf(h[c], d2, bp[c]);
    }
    int deg = cnt[r];
    int cap = deg < CAPC ? deg : CAPC;
    const int* ep = esrcb + (size_t)r * CAPC;
    int j = 0;
    for (; j + 4 <= cap; j += 4) {
        int s0 = ep[j], s1 = ep[j + 1], s2 = ep[j + 2], s3 = ep[j + 3];
        uint4 u0 = *(const uint4*)&H3b[(size_t)s0 * 40 + q * 8];
        uint4 u1 = *(const uint4*)&H3b[(size_t)s1 * 40 + q * 8];
        uint4 u2 = *(const uint4*)&H3b[(size_t)s2 * 40 + q * 8];
        uint4 u3 = *(const uint4*)&H3b[(size_t)s3 * 40 + q * 8];
        fma8(a0, u0, dinv[s0] * dd);
        fma8(a1, u1, dinv[s1] * dd);
        fma8(a2, u2, dinv[s2] * dd);
        fma8(a3, u3, dinv[s3] * dd);
    }
    for (; j < cap; ++j) {
        int s0 = ep[j];
        uint4 u = *(const uint4*)&H3b[(size_t)s0 * 40 + q * 8];
        fma8(a0, u, dinv[s0] * dd);
    }
    int ovn = *ovcnt;
    if (ovn > 0) {
        for (int k = 0; k < ovn; ++k) {
            int2 e = ovbuf[k];
            if (e.x == r) {
                uint4 u = *(const uint4*)&H3b[(size_t)e.y * 40 + q * 8];
                fma8(a0, u, dinv[e.y] * dd);
            }
        }
    }
    float o[8];
#pragma unroll
    for (int c = 0; c < 8; ++c) o[c] = a0[c] + a1[c] + a2[c] + a3[c];
    float* p = &OUT[(size_t)r * 40 + q * 8];
    *(float4*)(p)     = make_float4(o[0], o[1], o[2], o[3]);
    *(float4*)(p + 4) = make_float4(o[4], o[5], o[6], o[7]);
}

extern "C" void kernel_launch(void* const* d_in, const int* in_sizes, int n_in,
                              void* d_out, int out_size, void* d_ws, size_t ws_size,
                              hipStream_t stream) {
    const float* x  = (const float*)d_in[0];
    const int*   ei = (const int*)d_in[1];
    const float* W1 = (const float*)d_in[2];
    const float* b1 = (const float*)d_in[3];
    const float* W2 = (const float*)d_in[4];
    const float* b2 = (const float*)d_in[5];
    float* out = (float*)d_out;

    const int n = in_sizes[0] / 128;     // 50000
    const int m = in_sizes[1] / 2;       // 600000
    const int* src = ei;
    const int* dst = ei + m;
    const int nb  = (n + 255) / 256;     // 196
    const int ngb = (n + 63) / 64;       // 782

    char* p = (char*)d_ws;
    auto take = [&](size_t bytes) { char* q = p; p += (bytes + 255) & ~(size_t)255; return q; };
    int*   cnt    = (int*)take(sizeof(int) * n);
    int*   ovcnt  = (int*)take(sizeof(int) * 64);
    int2*  ovbuf  = (int2*)take(sizeof(int2) * 8192);
    int*   esrcb  = (int*)take(sizeof(int) * (size_t)n * CAPC);
    float* dinv   = (float*)take(sizeof(float) * n);
    unsigned short* WT  = (unsigned short*)take(sizeof(short) * 128 * 128);
    unsigned short* WT2 = (unsigned short*)take(sizeof(short) * 48 * 128);
    unsigned short* H1b = (unsigned short*)take(sizeof(short) * (size_t)n * 128);
    unsigned short* H3b = (unsigned short*)take(sizeof(short) * (size_t)n * 40);

    k_zero   <<<nb + 24, 256, 0, stream>>>(cnt, ovcnt, W1, W2, WT, WT2, n, nb);
    k_scatter<<<(m + 255) / 256, 256, 0, stream>>>(src, dst, cnt, esrcb, ovbuf, ovcnt, m);
    k_gemm1  <<<ngb + nb, 256, 0, stream>>>(x, WT, H1b, cnt, dinv, n, ngb);
    k_agg1g2 <<<ngb, 256, 0, stream>>>(cnt, esrcb, ovbuf, ovcnt, H1b, b1, WT2, dinv, H3b, n);
    k_agg2   <<<(n + 63) / 64, 320, 0, stream>>>(cnt, esrcb, ovbuf, ovcnt, H3b, b2, dinv, out, n);
}